// Round 6
// baseline (219.358 us; speedup 1.0000x reference)
//
#include <hip/hip_runtime.h>
#include <hip/hip_cooperative_groups.h>

namespace cg = cooperative_groups;

#define D_MODEL 1024
#define D_STATE 16
#define BATCH   2
#define SEQ     2048
#define CHUNK   32
#define NCHUNK  (SEQ / CHUNK)   // 64
#define NGRP    (SEQ / 4)       // 512 step-groups of 4
#define Q       8               // superblocks per sequence
#define SBLEN   (SEQ / Q)       // 256 steps per superblock
#define SBGRP   (SBLEN / 4)     // 64 float4-groups per superblock
#define SBCHK   (SBLEN / CHUNK) // 8 chunks per superblock
#define GRID    512             // co-resident: 2 blocks/CU needed, VGPR<=256 ok

// ---------------------------------------------------------------------------
// Single cooperative kernel, 3 phases separated by grid.sync() (replaces the
// 3-dispatch pipeline; each dispatch gap measured ~3 us in R4->R5).
//
// Phase A (GEMV): B_t[b,l,s] = sum_d x[b,l,d]*B_w[s,d]. Block = 4 waves; wave
//   owns an s-quad, lane a 16-d slice; B_w in registers; xor-butterfly
//   reduction. Writes bt[b][l][16] (row-major, phase-C uniform row loads) and
//   btg[b][l/4][s][4] (group-interleaved, 16 KB contiguous per (b,q), for
//   phase-B LDS staging).
// Phase B (local scan): unit = (b,q,dt16); 1024 units = 2 iters/block. Stage
//   the (b,q) btg slice (16 KB) into LDS, shared by 16 d's. Thread (dl,s)
//   scans 256 steps from zero (A^4 Horner), writes 8 zero-seeded chunk
//   carries + superblock final F.
// Phase C (final): unit = (b,c,dt256) = 512 = 1/block. h_init = local carry
//   + A^(32kk)*Horner_{A^256}(F[0..q-1]); rescan chunk, fuse C-proj + skip.
// ---------------------------------------------------------------------------
__global__ __launch_bounds__(256) void k_all(const float* __restrict__ x,
                                             const float* __restrict__ logA,
                                             const float* __restrict__ Bw,
                                             const float* __restrict__ Cw,
                                             const float* __restrict__ Dv,
                                             float* __restrict__ bt,
                                             float* __restrict__ btg,
                                             float* __restrict__ carry,
                                             float* __restrict__ F,
                                             float* __restrict__ y) {
    const int t = threadIdx.x;
    __shared__ float sb[SBLEN * D_STATE];   // 16 KB (phase B)

    // ---------------- Phase A: GEMV ----------------
    {
        const int wave = t >> 6;   // s-quad
        const int lane = t & 63;   // d-group

        float4 bw[4][4];
        const float* bwp = Bw + (wave * 4) * D_MODEL + lane * 16;
#pragma unroll
        for (int i = 0; i < 4; ++i)
#pragma unroll
            for (int k = 0; k < 4; ++k)
                bw[i][k] = *(const float4*)(bwp + i * D_MODEL + k * 4);

        const int ROWS = (BATCH * SEQ) / GRID;   // 8
        const int row0 = blockIdx.x * ROWS;
        for (int r = 0; r < ROWS; ++r) {
            const int row = row0 + r;   // flat (b*SEQ + l)
            const float* xr = x + (size_t)row * D_MODEL + lane * 16;
            float4 xv[4];
#pragma unroll
            for (int k = 0; k < 4; ++k) xv[k] = *(const float4*)(xr + k * 4);

            float acc[4] = {0.f, 0.f, 0.f, 0.f};
#pragma unroll
            for (int i = 0; i < 4; ++i) {
#pragma unroll
                for (int k = 0; k < 4; ++k) {
                    acc[i] += xv[k].x * bw[i][k].x;
                    acc[i] += xv[k].y * bw[i][k].y;
                    acc[i] += xv[k].z * bw[i][k].z;
                    acc[i] += xv[k].w * bw[i][k].w;
                }
            }
#pragma unroll
            for (int m = 1; m < 64; m <<= 1) {
#pragma unroll
                for (int i = 0; i < 4; ++i) acc[i] += __shfl_xor(acc[i], m, 64);
            }
            if (lane == 0) {
                *(float4*)(bt + (size_t)row * D_STATE + wave * 4) =
                    make_float4(acc[0], acc[1], acc[2], acc[3]);
                const int b = row >> 11;        // SEQ = 2048
                const int l = row & (SEQ - 1);
                float* p = btg + (((size_t)(b * NGRP + (l >> 2)) * D_STATE + wave * 4) << 2) + (l & 3);
#pragma unroll
                for (int i = 0; i < 4; ++i) p[i * 4] = acc[i];
            }
        }
    }

    cg::this_grid().sync();

    // ---------------- Phase B: local superblock scan ----------------
#pragma unroll
    for (int it = 0; it < 2; ++it) {
        const int unit = blockIdx.x + it * GRID;   // 0..1023
        const int dt  = unit & 63;
        const int q   = (unit >> 6) & 7;
        const int b   = unit >> 9;
        const int s   = t & 15;
        const int dl  = t >> 4;
        const int d   = dt * 16 + dl;

        if (it) __syncthreads();   // protect LDS re-stage
        {
            const float4* src = (const float4*)(btg + (size_t)(b * NGRP + q * SBGRP) * (D_STATE * 4));
            float4* dst = (float4*)sb;
#pragma unroll
            for (int i = 0; i < 4; ++i) dst[t + i * 256] = src[t + i * 256];
        }
        __syncthreads();

        const float A  = expf(-expf(logA[d * D_STATE + s]));
        const float A2 = A * A, A4 = A2 * A2;

        const float4* sb4 = (const float4*)sb;   // [group g][s]
        float h = 0.f;
        size_t ci = ((size_t)(b * NCHUNK + q * SBCHK) * D_MODEL + d) * D_STATE + s;
#pragma unroll
        for (int k = 0; k < SBCHK; ++k) {
            carry[ci] = h;                  // zero-seeded local carry
            ci += (size_t)D_MODEL * D_STATE;
#pragma unroll
            for (int gg = 0; gg < CHUNK / 4; ++gg) {
                const float4 v = sb4[(k * (CHUNK / 4) + gg) * D_STATE + s];
                h = h * A4 + (((v.x * A + v.y) * A + v.z) * A + v.w);
            }
        }
        F[((size_t)(b * Q + q) * D_MODEL + d) * D_STATE + s] = h;
    }

    cg::this_grid().sync();

    // ---------------- Phase C: final (fix + rescan + C-proj + skip) --------
    {
        const int blk = blockIdx.x;
        const int dt  = blk & 3;                  // D_MODEL/256
        const int c   = (blk >> 2) & (NCHUNK - 1);
        const int b   = blk >> 8;
        const int d   = dt * 256 + t;
        const int q   = c >> 3;
        const int kk  = c & 7;

        float A[D_STATE], C[D_STATE], h[D_STATE];
        const float* lp = logA + (size_t)d * D_STATE;
        const float* cp = Cw + (size_t)d * D_STATE;
        const float* hp = carry + ((size_t)(b * NCHUNK + c) * D_MODEL + d) * D_STATE;
#pragma unroll
        for (int s = 0; s < D_STATE; ++s) {
            A[s] = expf(-expf(lp[s]));
            C[s] = cp[s];
            h[s] = hp[s];               // zero-seeded local carry
        }

        if (q > 0) {
            float A32[D_STATE], H[D_STATE];
#pragma unroll
            for (int s = 0; s < D_STATE; ++s) {
                float a = A[s];
                a *= a; a *= a; a *= a; a *= a; a *= a;   // A^32
                A32[s] = a;
                H[s] = 0.f;
            }
            for (int p = 0; p < q; ++p) {
                const float* fp = F + ((size_t)(b * Q + p) * D_MODEL + d) * D_STATE;
#pragma unroll
                for (int s = 0; s < D_STATE; ++s) {
                    float a256 = A32[s]; a256 *= a256; a256 *= a256; a256 *= a256;
                    H[s] = H[s] * a256 + fp[s];
                }
            }
            for (int i = 0; i < kk; ++i)
#pragma unroll
                for (int s = 0; s < D_STATE; ++s) H[s] *= A32[s];
#pragma unroll
            for (int s = 0; s < D_STATE; ++s) h[s] += H[s];
        }

        const float dv = Dv[d];
        const float* btrow = bt + (size_t)(b * SEQ + c * CHUNK) * D_STATE;  // uniform
        const size_t rowbase = (size_t)(b * SEQ + c * CHUNK) * D_MODEL + d;
        const float* xp = x + rowbase;
        float*       yp = y + rowbase;

#pragma unroll 4
        for (int j = 0; j < CHUNK; ++j) {
            float acc = dv * xp[(size_t)j * D_MODEL];
#pragma unroll
            for (int s = 0; s < D_STATE; ++s) {
                h[s] = A[s] * h[s] + btrow[j * D_STATE + s];
                acc += C[s] * h[s];
            }
            yp[(size_t)j * D_MODEL] = acc;
        }
    }
}

extern "C" void kernel_launch(void* const* d_in, const int* in_sizes, int n_in,
                              void* d_out, int out_size, void* d_ws, size_t ws_size,
                              hipStream_t stream) {
    const float* x    = (const float*)d_in[0];
    const float* logA = (const float*)d_in[1];
    const float* Bw   = (const float*)d_in[2];
    const float* Cw   = (const float*)d_in[3];
    const float* Dv   = (const float*)d_in[4];
    float* y = (float*)d_out;

    float* bt    = (float*)d_ws;                                        // B*L*S    = 65536 floats
    float* btg   = bt    + (size_t)BATCH * SEQ * D_STATE;               // B*L*S    = 65536 floats
    float* carry = btg   + (size_t)BATCH * SEQ * D_STATE;               // B*Nc*D*S = 2097152 floats
    float* F     = carry + (size_t)BATCH * NCHUNK * D_MODEL * D_STATE;  // B*Q*D*S  = 262144 floats

    void* args[] = {(void*)&x, (void*)&logA, (void*)&Bw, (void*)&Cw, (void*)&Dv,
                    (void*)&bt, (void*)&btg, (void*)&carry, (void*)&F, (void*)&y};
    hipLaunchCooperativeKernel((const void*)k_all, dim3(GRID), dim3(256),
                               args, 0, stream);
}

// Round 7
// 98.516 us; speedup vs baseline: 2.2266x; 2.2266x over previous
//
#include <hip/hip_runtime.h>

#define D_MODEL 1024
#define D_STATE 16
#define BATCH   2
#define SEQ     2048
#define CHUNK   32
#define NCHUNK  (SEQ / CHUNK)   // 64
#define NGRP    (SEQ / 4)       // 512 step-groups of 4
#define Q       8               // superblocks per sequence
#define SBLEN   (SEQ / Q)       // 256 steps per superblock
#define SBGRP   (SBLEN / 4)     // 64 float4-groups per superblock
#define SBCHK   (SBLEN / CHUNK) // 8 chunks per superblock

// R7 = revert to R5 structure (best: 100.1 us). R6's cooperative single-kernel
// variant measured grid.sync() at ~60 us/barrier (130 us kernel, 4.9% HBM) —
// dispatch gaps (~3 us) are far cheaper than software grid barriers here.
// Decomposition (calibrated via R6): ~89 us harness reset floor + ~11 us for
// these 3 kernels + 2 gaps, which matches their ~70 MB traffic floor at
// 6.3 TB/s. No kernel-side lever above the noise band remains.

// ---------------------------------------------------------------------------
// K1: B_t[b,l,s] = sum_d x[b,l,d] * B_w[s,d]
// Block = 256 threads = 4 waves; wave w owns s-quad w, lane owns a 16-d slice.
// B_w lives in registers; full-d reduction = in-wave xor butterfly.
// Writes bt[b][l][16]       (row-major, for k_final's uniform row loads)
// and    btg[b][l/4][s][4]  (group-interleaved: 16 KB contiguous per (b,q)
//                            superblock, for k_scan_local's LDS staging)
// ---------------------------------------------------------------------------
__global__ __launch_bounds__(256) void k_bt(const float* __restrict__ x,
                                            const float* __restrict__ Bw,
                                            float* __restrict__ bt,
                                            float* __restrict__ btg) {
    const int t    = threadIdx.x;
    const int wave = t >> 6;   // s-quad
    const int lane = t & 63;   // d-group

    float4 bw[4][4];
    const float* bwp = Bw + (wave * 4) * D_MODEL + lane * 16;
#pragma unroll
    for (int i = 0; i < 4; ++i)
#pragma unroll
        for (int k = 0; k < 4; ++k)
            bw[i][k] = *(const float4*)(bwp + i * D_MODEL + k * 4);

    const int ROWS = (BATCH * SEQ) / gridDim.x;
    const int row0 = blockIdx.x * ROWS;
    for (int r = 0; r < ROWS; ++r) {
        const int row = row0 + r;   // flat (b*SEQ + l)
        const float* xr = x + (size_t)row * D_MODEL + lane * 16;
        float4 xv[4];
#pragma unroll
        for (int k = 0; k < 4; ++k) xv[k] = *(const float4*)(xr + k * 4);

        float acc[4] = {0.f, 0.f, 0.f, 0.f};
#pragma unroll
        for (int i = 0; i < 4; ++i) {
#pragma unroll
            for (int k = 0; k < 4; ++k) {
                acc[i] += xv[k].x * bw[i][k].x;
                acc[i] += xv[k].y * bw[i][k].y;
                acc[i] += xv[k].z * bw[i][k].z;
                acc[i] += xv[k].w * bw[i][k].w;
            }
        }
#pragma unroll
        for (int m = 1; m < 64; m <<= 1) {
#pragma unroll
            for (int i = 0; i < 4; ++i) acc[i] += __shfl_xor(acc[i], m, 64);
        }
        if (lane == 0) {
            *(float4*)(bt + (size_t)row * D_STATE + wave * 4) =
                make_float4(acc[0], acc[1], acc[2], acc[3]);
            const int b = row >> 11;        // SEQ = 2048
            const int l = row & (SEQ - 1);
            float* p = btg + (((size_t)(b * NGRP + (l >> 2)) * D_STATE + wave * 4) << 2) + (l & 3);
#pragma unroll
            for (int i = 0; i < 4; ++i) p[i * 4] = acc[i];
        }
    }
}

// ---------------------------------------------------------------------------
// K2: local scan with LDS-shared inputs. Block = (b, superblock q, 16-d tile);
// thread = (d_local, s). The (b,q) btg slice (16 KB, contiguous) is staged
// once into LDS and shared across the 16 d's. Each thread scans SBLEN=256
// steps from zero state (A^4-blocked Horner), writes its 8 zero-seeded local
// chunk-carries into carry[] and its superblock final into F[].
// ---------------------------------------------------------------------------
__global__ __launch_bounds__(256) void k_scan_local(const float* __restrict__ btg,
                                                    const float* __restrict__ logA,
                                                    float* __restrict__ carry,
                                                    float* __restrict__ F) {
    const int blk = blockIdx.x;
    const int dt  = blk & 63;          // 64 d-tiles of 16
    const int q   = (blk >> 6) & 7;
    const int b   = blk >> 9;
    const int t   = threadIdx.x;
    const int s   = t & 15;
    const int dl  = t >> 4;
    const int d   = dt * 16 + dl;

    __shared__ float sb[SBLEN * D_STATE];   // 16 KB
    {
        const float4* src = (const float4*)(btg + (size_t)(b * NGRP + q * SBGRP) * (D_STATE * 4));
        float4* dst = (float4*)sb;
#pragma unroll
        for (int i = 0; i < 4; ++i) dst[t + i * 256] = src[t + i * 256];
    }
    __syncthreads();

    const float A  = expf(-expf(logA[d * D_STATE + s]));
    const float A2 = A * A, A4 = A2 * A2;

    const float4* sb4 = (const float4*)sb;   // [group g][s] -> sb4[g*16+s]
    float h = 0.f;
    size_t ci = ((size_t)(b * NCHUNK + q * SBCHK) * D_MODEL + d) * D_STATE + s;
#pragma unroll
    for (int k = 0; k < SBCHK; ++k) {
        carry[ci] = h;                  // local (zero-seeded) carry for chunk
        ci += (size_t)D_MODEL * D_STATE;
#pragma unroll
        for (int gg = 0; gg < CHUNK / 4; ++gg) {
            const float4 v = sb4[(k * (CHUNK / 4) + gg) * D_STATE + s];
            h = h * A4 + (((v.x * A + v.y) * A + v.z) * A + v.w);
        }
    }
    F[((size_t)(b * Q + q) * D_MODEL + d) * D_STATE + s] = h;
}

// ---------------------------------------------------------------------------
// K3: final pass with inline cross-superblock fix.
// Block = (b, chunk c, d-tile of 256); thread = one d. c = q*8+kk.
// h_init[s] = localcarry[c] + A^(32*kk) * Horner_{A^256}(F[0..q-1]).
// Then re-runs the local chunk scan, fuses C-projection + skip, writes y.
// bt rows are wave-uniform addresses; x/y/carry/F loads coalesced.
// ---------------------------------------------------------------------------
__global__ __launch_bounds__(256) void k_final(const float* __restrict__ x,
                                               const float* __restrict__ logA,
                                               const float* __restrict__ Cw,
                                               const float* __restrict__ Dv,
                                               const float* __restrict__ bt,
                                               const float* __restrict__ carry,
                                               const float* __restrict__ F,
                                               float* __restrict__ y) {
    const int blk = blockIdx.x;
    const int dt  = blk & 3;                  // D_MODEL/256 = 4 tiles
    const int c   = (blk >> 2) & (NCHUNK - 1);
    const int b   = blk >> 8;
    const int t   = threadIdx.x;
    const int d   = dt * 256 + t;
    const int q   = c >> 3;        // superblock
    const int kk  = c & 7;         // chunk within superblock

    float A[D_STATE], C[D_STATE], h[D_STATE];
    const float* lp = logA + (size_t)d * D_STATE;
    const float* cp = Cw + (size_t)d * D_STATE;
    const float* hp = carry + ((size_t)(b * NCHUNK + c) * D_MODEL + d) * D_STATE;
#pragma unroll
    for (int s = 0; s < D_STATE; ++s) {
        A[s] = expf(-expf(lp[s]));
        C[s] = cp[s];
        h[s] = hp[s];               // zero-seeded local carry
    }

    // Inline fix: fold in A^(32*kk) * Horner_{A^256}(F[0..q-1])   (q,kk uniform)
    if (q > 0) {
        float A32[D_STATE], H[D_STATE];
#pragma unroll
        for (int s = 0; s < D_STATE; ++s) {
            float a = A[s];
            a *= a; a *= a; a *= a; a *= a; a *= a;   // A^32
            A32[s] = a;
            H[s] = 0.f;
        }
        for (int p = 0; p < q; ++p) {
            const float* fp = F + ((size_t)(b * Q + p) * D_MODEL + d) * D_STATE;
#pragma unroll
            for (int s = 0; s < D_STATE; ++s) {
                float a256 = A32[s]; a256 *= a256; a256 *= a256; a256 *= a256;
                H[s] = H[s] * a256 + fp[s];
            }
        }
        for (int i = 0; i < kk; ++i)
#pragma unroll
            for (int s = 0; s < D_STATE; ++s) H[s] *= A32[s];
#pragma unroll
        for (int s = 0; s < D_STATE; ++s) h[s] += H[s];
    }

    const float dv = Dv[d];
    const float* btrow = bt + (size_t)(b * SEQ + c * CHUNK) * D_STATE;  // uniform
    const size_t rowbase = (size_t)(b * SEQ + c * CHUNK) * D_MODEL + d;
    const float* xp = x + rowbase;
    float*       yp = y + rowbase;

#pragma unroll 4
    for (int j = 0; j < CHUNK; ++j) {
        float acc = dv * xp[(size_t)j * D_MODEL];
#pragma unroll
        for (int s = 0; s < D_STATE; ++s) {
            h[s] = A[s] * h[s] + btrow[j * D_STATE + s];
            acc += C[s] * h[s];
        }
        yp[(size_t)j * D_MODEL] = acc;
    }
}

extern "C" void kernel_launch(void* const* d_in, const int* in_sizes, int n_in,
                              void* d_out, int out_size, void* d_ws, size_t ws_size,
                              hipStream_t stream) {
    const float* x    = (const float*)d_in[0];
    const float* logA = (const float*)d_in[1];
    const float* Bw   = (const float*)d_in[2];
    const float* Cw   = (const float*)d_in[3];
    const float* Dv   = (const float*)d_in[4];
    float* y = (float*)d_out;

    float* bt    = (float*)d_ws;                                   // B*L*S    = 65536 floats
    float* btg   = bt    + (size_t)BATCH * SEQ * D_STATE;          // B*L*S    = 65536 floats
    float* carry = btg   + (size_t)BATCH * SEQ * D_STATE;          // B*Nc*D*S = 2097152 floats
    float* F     = carry + (size_t)BATCH * NCHUNK * D_MODEL * D_STATE;  // B*Q*D*S = 262144 floats

    hipLaunchKernelGGL(k_bt,         dim3(512), dim3(256), 0, stream, x, Bw, bt, btg);
    hipLaunchKernelGGL(k_scan_local, dim3(BATCH * Q * 64), dim3(256), 0, stream, btg, logA, carry, F);
    hipLaunchKernelGGL(k_final,      dim3(BATCH * NCHUNK * (D_MODEL / 256)), dim3(256), 0, stream, x, logA, Cw, Dv, bt, carry, F, y);
}